// Round 6
// baseline (700.021 us; speedup 1.0000x reference)
//
#include <hip/hip_runtime.h>
#include <math.h>

#define N_NODES 20000
#define M_PAD   20096   // 157 * 128
#define N_EDGES 320000
#define DIM_IN 768
#define DIM_H 512
#define NUM_GNNS 4
#define NEG_SLOPE 0.2f

#define GEMM_TILES 628        // (M_PAD/128) * (DIM_H/128) = 157*4
#define GEMM_GRID  632        // ceil to multiple of 8 for XCD swizzle

// sliced gather: 8 column slices (64 cols), slice = bid&7 -> XCD (round-robin).
// grid = 8 slices * 625 node-groups; block = 4 waves; wave = 8 slots * 8 subs;
// slot owns ONE node (degree-binned via perm), sub owns 8 cols (uint4).
#define SLC_GRID 5000

typedef __attribute__((ext_vector_type(8))) short short8;
typedef __attribute__((ext_vector_type(4))) float f32x4;

#define GPTR(p) (const __attribute__((address_space(1))) void*)(p)
#define LPTR(p) (__attribute__((address_space(3))) void*)(p)

__device__ __forceinline__ float bf2f(unsigned int lo16) {
  return __uint_as_float(lo16 << 16);
}
__device__ __forceinline__ unsigned short f2bf(float f) {
  unsigned int u = __float_as_uint(f);
  u += 0x7FFFu + ((u >> 16) & 1u);   // round-to-nearest-even
  return (unsigned short)(u >> 16);
}
__device__ __forceinline__ void unpack8(uint4 v, float* f) {
  f[0] = bf2f(v.x & 0xffffu); f[1] = bf2f(v.x >> 16);
  f[2] = bf2f(v.y & 0xffffu); f[3] = bf2f(v.y >> 16);
  f[4] = bf2f(v.z & 0xffffu); f[5] = bf2f(v.z >> 16);
  f[6] = bf2f(v.w & 0xffffu); f[7] = bf2f(v.w >> 16);
}
__device__ __forceinline__ uint4 pack8(const float* o) {
  uint4 pv;
  pv.x = (unsigned)f2bf(o[0]) | ((unsigned)f2bf(o[1]) << 16);
  pv.y = (unsigned)f2bf(o[2]) | ((unsigned)f2bf(o[3]) << 16);
  pv.z = (unsigned)f2bf(o[4]) | ((unsigned)f2bf(o[5]) << 16);
  pv.w = (unsigned)f2bf(o[6]) | ((unsigned)f2bf(o[7]) << 16);
  return pv;
}

__device__ __forceinline__ float waveReduceSum(float v) {
#pragma unroll
  for (int off = 32; off > 0; off >>= 1) v += __shfl_xor(v, off, 64);
  return v;
}
__device__ __forceinline__ float waveReduceMax(float v) {
#pragma unroll
  for (int off = 32; off > 0; off >>= 1) v = fmaxf(v, __shfl_xor(v, off, 64));
  return v;
}

// ============ MFMA GEMM: double-buffered LDS (1 barrier/K-step) + coalesced C ============
// Cbf[M_PAD,512](bf16) = A[M_PAD,K](bf16) @ Bt[512,K]^T (+bias). XCD tile swizzle.
__global__ __launch_bounds__(256) void gemm_mfma_bf16(
    const unsigned short* __restrict__ A,
    const unsigned short* __restrict__ Bt,
    const float* __restrict__ bias,
    unsigned short* __restrict__ Cbf,
    int K) {
  int bid = blockIdx.x;
  int tile = (bid & 7) * (GEMM_GRID / 8) + (bid >> 3);
  if (tile >= GEMM_TILES) return;
  int brow = tile >> 2;   // 0..156
  int bcol = tile & 3;    // 0..3

  // lds[0],lds[1] = A dbuf; lds[2],lds[3] = B dbuf; epilogue reuses lds[0..1] as Cs[128][128]
  __shared__ __align__(16) unsigned short lds[4][128 * 32];
  int tid = threadIdx.x;
  int wave = tid >> 6, lane = tid & 63;
  int wm = wave >> 1, wn = wave & 1;

  int rl = lane >> 2;
  int kc = (lane & 3) ^ ((lane >> 3) & 3);
  int r0 = 32 * wave;
  const unsigned short* gA0 = A + (size_t)(brow * 128 + r0 + rl) * K + kc * 8;
  const unsigned short* gA1 = gA0 + (size_t)16 * K;
  const unsigned short* gB0 = Bt + (size_t)(bcol * 128 + r0 + rl) * K + kc * 8;
  const unsigned short* gB1 = gB0 + (size_t)16 * K;

  int mrow = lane & 15;
  int q = lane >> 4;
  int swz = (q ^ ((mrow >> 1) & 3)) * 8;

  f32x4 acc[4][4];
#pragma unroll
  for (int i = 0; i < 4; ++i)
#pragma unroll
    for (int j = 0; j < 4; ++j) acc[i][j] = (f32x4)(0.f);

  int nk = K >> 5;
  {  // prologue: stage k-step 0 into buffer 0
    unsigned short* lA = lds[0] + r0 * 32;
    unsigned short* lB = lds[2] + r0 * 32;
    __builtin_amdgcn_global_load_lds(GPTR(gA0), LPTR(lA), 16, 0, 0);
    __builtin_amdgcn_global_load_lds(GPTR(gA1), LPTR(lA + 512), 16, 0, 0);
    __builtin_amdgcn_global_load_lds(GPTR(gB0), LPTR(lB), 16, 0, 0);
    __builtin_amdgcn_global_load_lds(GPTR(gB1), LPTR(lB + 512), 16, 0, 0);
  }
  __syncthreads();   // compiler drains vmcnt before barrier -> buf0 ready

  for (int t = 0; t < nk; ++t) {
    int cur = t & 1;
    if (t + 1 < nk) {   // stage next k-step into the other buffer (overlaps MFMA)
      int k0 = (t + 1) << 5;
      unsigned short* lA = lds[cur ^ 1] + r0 * 32;
      unsigned short* lB = lds[2 + (cur ^ 1)] + r0 * 32;
      __builtin_amdgcn_global_load_lds(GPTR(gA0 + k0), LPTR(lA), 16, 0, 0);
      __builtin_amdgcn_global_load_lds(GPTR(gA1 + k0), LPTR(lA + 512), 16, 0, 0);
      __builtin_amdgcn_global_load_lds(GPTR(gB0 + k0), LPTR(lB), 16, 0, 0);
      __builtin_amdgcn_global_load_lds(GPTR(gB1 + k0), LPTR(lB + 512), 16, 0, 0);
    }
    const short8* ra = (const short8*)(lds[cur] + (64 * wm + mrow) * 32 + swz);
    const short8* rb = (const short8*)(lds[2 + cur] + (64 * wn + mrow) * 32 + swz);
    short8 a[4], b[4];
#pragma unroll
    for (int u = 0; u < 4; ++u) a[u] = ra[u * 64];
#pragma unroll
    for (int u = 0; u < 4; ++u) b[u] = rb[u * 64];
#pragma unroll
    for (int mt = 0; mt < 4; ++mt)
#pragma unroll
      for (int nt = 0; nt < 4; ++nt)
        acc[mt][nt] = __builtin_amdgcn_mfma_f32_16x16x32_bf16(a[mt], b[nt], acc[mt][nt], 0, 0, 0);
    __syncthreads();   // one barrier per K-step: next buf staged AND all reads of cur done
  }

  // epilogue: stage C tile in LDS (reuse lds[0..1] = 32KB), then coalesced uint4 writes
  unsigned short* Cs = lds[0];
  {
    float bv[4];
#pragma unroll
    for (int nt = 0; nt < 4; ++nt)
      bv[nt] = bias ? bias[bcol * 128 + 64 * wn + 16 * nt + mrow] : 0.f;
#pragma unroll
    for (int mt = 0; mt < 4; ++mt)
#pragma unroll
      for (int nt = 0; nt < 4; ++nt)
#pragma unroll
        for (int i = 0; i < 4; ++i) {
          int row = 64 * wm + 16 * mt + 4 * q + i;
          int col = 64 * wn + 16 * nt + mrow;
          Cs[row * 128 + col] = f2bf(acc[mt][nt][i] + bv[nt]);
        }
  }
  __syncthreads();
  int rr = tid >> 4, cb = (tid & 15) * 8;
#pragma unroll
  for (int it = 0; it < 8; ++it, rr += 16) {
    uint4 val = *(const uint4*)(Cs + rr * 128 + cb);
    *(uint4*)(Cbf + (size_t)(brow * 128 + rr) * DIM_H + bcol * 128 + cb) = val;
  }
}

// ================= conversions =================
__global__ void convert_feat(const float* __restrict__ feat, unsigned short* __restrict__ Abf) {
  int t = blockIdx.x * blockDim.x + threadIdx.x;
  const int CHUNKS = M_PAD * DIM_IN / 8;
  if (t >= CHUNKS) return;
  int row = t / (DIM_IN / 8);
  uint4 o;
  if (row < N_NODES) {
    const float4* p = (const float4*)(feat + (size_t)t * 8);
    float4 x = p[0], y = p[1];
    o.x = (unsigned)f2bf(x.x) | ((unsigned)f2bf(x.y) << 16);
    o.y = (unsigned)f2bf(x.z) | ((unsigned)f2bf(x.w) << 16);
    o.z = (unsigned)f2bf(y.x) | ((unsigned)f2bf(y.y) << 16);
    o.w = (unsigned)f2bf(y.z) | ((unsigned)f2bf(y.w) << 16);
  } else {
    o = make_uint4(0, 0, 0, 0);
  }
  ((uint4*)Abf)[t] = o;
}

// LDS-tiled transpose: in [R,C] f32 -> out [C,R] bf16. R,C multiples of 32.
__global__ __launch_bounds__(256) void transpose_bf16(const float* __restrict__ in,
                                                      unsigned short* __restrict__ out,
                                                      int R, int C) {
  __shared__ float tile[32][33];
  int tx = threadIdx.x, ty = threadIdx.y;
  size_t base = (size_t)blockIdx.z * R * C;
  int r0 = blockIdx.x * 32, c0 = blockIdx.y * 32;
#pragma unroll
  for (int i = 0; i < 4; ++i) {
    int r = r0 + ty + i * 8;
    tile[ty + i * 8][tx] = in[base + (size_t)r * C + c0 + tx];
  }
  __syncthreads();
#pragma unroll
  for (int i = 0; i < 4; ++i) {
    int c = c0 + ty + i * 8;
    out[base + (size_t)c * R + r0 + tx] = f2bf(tile[tx][ty + i * 8]);
  }
}

// ================= CSR build (dst -> src adjacency) =================
__global__ void count_edges(const int* __restrict__ dst, int* __restrict__ counts) {
  int k = blockIdx.x * blockDim.x + threadIdx.x;
  if (k < N_EDGES) atomicAdd(&counts[dst[k]], 1);
}

__global__ __launch_bounds__(1024) void scan_kernel(const int* __restrict__ counts,
                                                    int* __restrict__ indptr) {
  __shared__ int part[1024];
  int tid = threadIdx.x;
  const int CH = (N_NODES + 1023) / 1024;
  int base = tid * CH;
  int s = 0;
  for (int i = 0; i < CH; ++i) {
    int idx = base + i;
    if (idx < N_NODES) s += counts[idx];
  }
  part[tid] = s;
  __syncthreads();
  for (int off = 1; off < 1024; off <<= 1) {
    int v = (tid >= off) ? part[tid - off] : 0;
    __syncthreads();
    part[tid] += v;
    __syncthreads();
  }
  int run = (tid == 0) ? 0 : part[tid - 1];
  for (int i = 0; i < CH; ++i) {
    int idx = base + i;
    if (idx < N_NODES) {
      indptr[idx] = run;
      run += counts[idx];
      if (idx == N_NODES - 1) indptr[N_NODES] = run;
    }
  }
}

__global__ void fill_adj(const int* __restrict__ src, const int* __restrict__ dst,
                         const int* __restrict__ indptr, int* __restrict__ cursor,
                         int* __restrict__ adjsrc) {
  int k = blockIdx.x * blockDim.x + threadIdx.x;
  if (k < N_EDGES) {
    int d = dst[k];
    int pos = atomicAdd(&cursor[d], 1);
    adjsrc[indptr[d] + pos] = src[k];
  }
}

// ============ degree binning: perm = nodes counting-sorted by (clamped) degree ============
__global__ void hist64(const int* __restrict__ counts, int* __restrict__ hist) {
  int v = blockIdx.x * blockDim.x + threadIdx.x;
  if (v < N_NODES) atomicAdd(&hist[min(counts[v], 63)], 1);
}
__global__ void scan64(const int* __restrict__ hist, int* __restrict__ base) {
  if (threadIdx.x == 0) {
    int run = 0;
    for (int i = 0; i < 64; ++i) { base[i] = run; run += hist[i]; }
  }
}
__global__ void scatter_perm(const int* __restrict__ counts, int* __restrict__ base,
                             int* __restrict__ perm) {
  int v = blockIdx.x * blockDim.x + threadIdx.x;
  if (v < N_NODES) {
    int b = min(counts[v], 63);
    int pos = atomicAdd(&base[b], 1);   // base consumed as running cursor
    perm[pos] = v;
  }
}

// ================= el/er from bf16 z =================
__global__ __launch_bounds__(256) void eler_bf(const unsigned short* __restrict__ zbf,
                                               const float* __restrict__ al,
                                               const float* __restrict__ ar,
                                               float* __restrict__ el, float* __restrict__ er) {
  int wid = (blockIdx.x * blockDim.x + threadIdx.x) >> 6;
  int lane = threadIdx.x & 63;
  if (wid >= N_NODES) return;
  uint4 zv = ((const uint4*)(zbf + (size_t)wid * DIM_H))[lane];
  float z[8];
  unpack8(zv, z);
  const float4* al4 = (const float4*)(al + lane * 8);
  const float4* ar4 = (const float4*)(ar + lane * 8);
  float4 a0 = al4[0], a1 = al4[1], r0 = ar4[0], r1 = ar4[1];
  float sl = z[0] * a0.x + z[1] * a0.y + z[2] * a0.z + z[3] * a0.w +
             z[4] * a1.x + z[5] * a1.y + z[6] * a1.z + z[7] * a1.w;
  float sr = z[0] * r0.x + z[1] * r0.y + z[2] * r0.z + z[3] * r0.w +
             z[4] * r1.x + z[5] * r1.y + z[6] * r1.z + z[7] * r1.w;
  sl = waveReduceSum(sl);
  sr = waveReduceSum(sr);
  if (lane == 0) { el[wid] = sl; er[wid] = sr; }
}

// ================= edge softmax -> packed (idx, alpha) records =================
__global__ __launch_bounds__(256) void edge_softmax_alpha(
    const float* __restrict__ el, const float* __restrict__ er,
    const int* __restrict__ indptr, const int* __restrict__ adjsrc,
    float* __restrict__ alpha, int2* __restrict__ apairs) {
  int v = (blockIdx.x * blockDim.x + threadIdx.x) >> 6;
  int lane = threadIdx.x & 63;
  if (v >= N_NODES) return;
  int begin = indptr[v], end = indptr[v + 1];
  float er_v = er[v];

  float m = -INFINITY;
  for (int j = begin + lane; j < end; j += 64) {
    float e = el[adjsrc[j]] + er_v;
    e = (e >= 0.f) ? e : NEG_SLOPE * e;
    alpha[j] = e;
    m = fmaxf(m, e);
  }
  m = waveReduceMax(m);

  float ss = 0.f;
  for (int j = begin + lane; j < end; j += 64) {
    float ex = __expf(alpha[j] - m);
    alpha[j] = ex;
    ss += ex;
  }
  float denom = waveReduceSum(ss);
  float inv = (end > begin) ? 1.f / denom : 0.f;

  for (int j = begin + lane; j < end; j += 64)
    apairs[j] = make_int2(adjsrc[j], __float_as_int(alpha[j] * inv));
}

// ========== XCD-sliced gather, slot-per-node, degree-binned, 8-deep ILP ==========
// slice = bid&7 -> XCD (2.56 MB table slice resident in that XCD's 4 MiB L2).
// lane = (slot, sub): slot owns node perm[vidx] (degree-binned -> max degree of the
// wave's 8 slots ~= mean), sub owns 8 cols (uint4). 8 edges per iteration, all
// addresses uniform_base + 32-bit voffset; masked tail via weight 0.
__global__ __launch_bounds__(256) void gather_slc(
    const unsigned short* __restrict__ zin, const int2* __restrict__ apairs,
    const int* __restrict__ indptr, const int* __restrict__ adjsrc,
    const int* __restrict__ perm, const float* __restrict__ bias, int self_term,
    unsigned short* __restrict__ out_bf, float* __restrict__ out_f32) {
  int slice = blockIdx.x & 7;
  int grp = blockIdx.x >> 3;                    // 0..624
  int wave = threadIdx.x >> 6, lane = threadIdx.x & 63;
  int slot = lane >> 3, sub = lane & 7;
  int vidx = grp * 32 + wave * 8 + slot;
  int v = perm[vidx];                           // degree-binned node
  unsigned cbyte = (unsigned)(slice * 128 + sub * 16);
  const char* zb = (const char*)zin;

  int b = indptr[v];
  unsigned ue = (unsigned)indptr[v + 1];
  int md = (int)ue - b;                         // max degree over the 8 slots
  md = max(md, __shfl_xor(md, 8, 64));
  md = max(md, __shfl_xor(md, 16, 64));
  md = max(md, __shfl_xor(md, 32, 64));

  float acc[8];
  if (self_term) {
    uint4 sz = *(const uint4*)(zb + (((unsigned)v) << 10) + cbyte);
    unpack8(sz, acc);
  } else {
#pragma unroll
    for (int i = 0; i < 8; ++i) acc[i] = 0.f;
  }

  unsigned jb = (unsigned)b;
  const unsigned EMAX = (unsigned)(N_EDGES - 1);
  if (apairs) {
    const char* pb = (const char*)apairs;
#pragma nounroll
    for (int t = 0; t < md; t += 8) {
      unsigned j0 = jb + (unsigned)t;
      int idx[8];
      float wv[8];
#pragma unroll
      for (int u = 0; u < 8; ++u) {
        unsigned a = min(j0 + (unsigned)u, EMAX) << 3;
        int2 p = *(const int2*)(pb + a);
        idx[u] = p.x;
        wv[u] = (j0 + (unsigned)u < ue) ? __int_as_float(p.y) : 0.f;
      }
      uint4 z[8];
#pragma unroll
      for (int u = 0; u < 8; ++u)
        z[u] = *(const uint4*)(zb + (((unsigned)idx[u]) << 10) + cbyte);
#pragma unroll
      for (int u = 0; u < 8; ++u) {
        float f[8];
        unpack8(z[u], f);
#pragma unroll
        for (int i = 0; i < 8; ++i) acc[i] = fmaf(wv[u], f[i], acc[i]);
      }
    }
  } else {
    const char* ab = (const char*)adjsrc;
#pragma nounroll
    for (int t = 0; t < md; t += 8) {
      unsigned j0 = jb + (unsigned)t;
      int idx[8];
      float wv[8];
#pragma unroll
      for (int u = 0; u < 8; ++u) {
        unsigned a = min(j0 + (unsigned)u, EMAX) << 2;
        idx[u] = *(const int*)(ab + a);
        wv[u] = (j0 + (unsigned)u < ue) ? 1.f : 0.f;
      }
      uint4 z[8];
#pragma unroll
      for (int u = 0; u < 8; ++u)
        z[u] = *(const uint4*)(zb + (((unsigned)idx[u]) << 10) + cbyte);
#pragma unroll
      for (int u = 0; u < 8; ++u) {
        float f[8];
        unpack8(z[u], f);
#pragma unroll
        for (int i = 0; i < 8; ++i) acc[i] = fmaf(wv[u], f[i], acc[i]);
      }
    }
  }

  if (bias) {
    const float4* b4 = (const float4*)(bias + slice * 64 + sub * 8);
    float4 b0 = b4[0], b1 = b4[1];
    acc[0] += b0.x; acc[1] += b0.y; acc[2] += b0.z; acc[3] += b0.w;
    acc[4] += b1.x; acc[5] += b1.y; acc[6] += b1.z; acc[7] += b1.w;
  }
  if (out_bf) {
    uint4 pv = pack8(acc);
    *(uint4*)((char*)out_bf + (((unsigned)v) << 10) + cbyte) = pv;
  } else {
    char* p = (char*)out_f32 + (((unsigned)v) << 11) + cbyte * 2;
    *(f32x4*)p = (f32x4){acc[0], acc[1], acc[2], acc[3]};
    *(f32x4*)(p + 16) = (f32x4){acc[4], acc[5], acc[6], acc[7]};
  }
}

// ================= launch =================
extern "C" void kernel_launch(void* const* d_in, const int* in_sizes, int n_in,
                              void* d_out, int out_size, void* d_ws, size_t ws_size,
                              hipStream_t stream) {
  const float* feat = (const float*)d_in[0];
  const float* fc_W = (const float*)d_in[1];
  const float* fc_b = (const float*)d_in[2];
  const float* gat_W = (const float*)d_in[3];
  const float* gat_al = (const float*)d_in[4];
  const float* gat_ar = (const float*)d_in[5];
  const float* gat_b = (const float*)d_in[6];
  // d_in[7] = beta unused (reference returns Z_prev)
  const int* src = (const int*)d_in[8];
  const int* dst = (const int*)d_in[9];
  float* out = (float*)d_out;

  char* w = (char*)d_ws;
  auto alloc = [&](size_t bytes) {
    char* p = w;
    w += (bytes + 255) & ~(size_t)255;
    return p;
  };
  unsigned short* hbf   = (unsigned short*)alloc((size_t)M_PAD * DIM_H * 2);
  unsigned short* fcWt  = (unsigned short*)alloc((size_t)DIM_H * DIM_IN * 2);
  unsigned short* gatWt = (unsigned short*)alloc((size_t)NUM_GNNS * DIM_H * DIM_H * 2);
  float* el    = (float*)alloc((size_t)N_NODES * 4);
  float* er    = (float*)alloc((size_t)N_NODES * 4);
  int* counts  = (int*)alloc((size_t)(2 * N_NODES + 128) * 4); // counts+cursor+hist+base
  int* cursor  = counts + N_NODES;
  int* hist    = counts + 2 * N_NODES;
  int* basebuf = hist + 64;
  int* indptr  = (int*)alloc((size_t)(N_NODES + 1) * 4);
  int* adjsrc  = (int*)alloc((size_t)N_EDGES * 4);
  int* perm    = (int*)alloc((size_t)N_NODES * 4);
  char* uni = alloc((size_t)M_PAD * DIM_IN * 2);   // Abf (30.9MB) -> alpha+apairs -> Z1 (20.6MB)
  unsigned short* Abf = (unsigned short*)uni;      // live: convert + first GEMM only
  float* alpha = (float*)uni;                      // live: softmax scratch per layer
  int2* apairs = (int2*)(uni + (((size_t)N_EDGES * 4 + 255) & ~(size_t)255)); // packed records
  unsigned short* Z1  = (unsigned short*)uni;      // live: propagation only
  unsigned short* zbf = (unsigned short*)d_out;

  // ---- CSR build + degree binning ----
  hipMemsetAsync(counts, 0, sizeof(int) * (2 * N_NODES + 128), stream);
  count_edges<<<(N_EDGES + 255) / 256, 256, 0, stream>>>(dst, counts);
  scan_kernel<<<1, 1024, 0, stream>>>(counts, indptr);
  fill_adj<<<(N_EDGES + 255) / 256, 256, 0, stream>>>(src, dst, indptr, cursor, adjsrc);
  hist64<<<(N_NODES + 255) / 256, 256, 0, stream>>>(counts, hist);
  scan64<<<1, 64, 0, stream>>>(hist, basebuf);
  scatter_perm<<<(N_NODES + 255) / 256, 256, 0, stream>>>(counts, basebuf, perm);

  // ---- bf16 prep ----
  convert_feat<<<(M_PAD * DIM_IN / 8 + 255) / 256, 256, 0, stream>>>(feat, Abf);
  transpose_bf16<<<dim3(DIM_IN / 32, DIM_H / 32, 1), dim3(32, 8), 0, stream>>>(fc_W, fcWt, DIM_IN, DIM_H);
  transpose_bf16<<<dim3(DIM_H / 32, DIM_H / 32, NUM_GNNS), dim3(32, 8), 0, stream>>>(gat_W, gatWt, DIM_H, DIM_H);

  gemm_mfma_bf16<<<GEMM_GRID, 256, 0, stream>>>(Abf, fcWt, fc_b, hbf, DIM_IN);

  int nwaveblocks = (N_NODES * 64 + 255) / 256;
  for (int l = 0; l < NUM_GNNS; ++l) {
    gemm_mfma_bf16<<<GEMM_GRID, 256, 0, stream>>>(hbf, gatWt + (size_t)l * DIM_H * DIM_H,
                                                  nullptr, zbf, DIM_H);
    eler_bf<<<nwaveblocks, 256, 0, stream>>>(zbf, gat_al + (size_t)l * DIM_H,
                                             gat_ar + (size_t)l * DIM_H, el, er);
    edge_softmax_alpha<<<nwaveblocks, 256, 0, stream>>>(el, er, indptr, adjsrc, alpha, apairs);
    gather_slc<<<SLC_GRID, 256, 0, stream>>>(
        zbf, apairs, indptr, adjsrc, perm, gat_b + (size_t)l * DIM_H, 0, hbf, nullptr);
  }

  // ---- 3 propagation hops (self term, weight 1) ----
  gather_slc<<<SLC_GRID, 256, 0, stream>>>(hbf, nullptr, indptr, adjsrc, perm, nullptr, 1, Z1, nullptr);
  gather_slc<<<SLC_GRID, 256, 0, stream>>>(Z1, nullptr, indptr, adjsrc, perm, nullptr, 1, hbf, nullptr);
  gather_slc<<<SLC_GRID, 256, 0, stream>>>(hbf, nullptr, indptr, adjsrc, perm, nullptr, 1, nullptr, out);
}

// Round 7
// 595.887 us; speedup vs baseline: 1.1748x; 1.1748x over previous
//
#include <hip/hip_runtime.h>
#include <math.h>

#define N_NODES 20000
#define M_PAD   20096   // 157 * 128
#define N_EDGES 320000
#define DIM_IN 768
#define DIM_H 512
#define NUM_GNNS 4
#define NEG_SLOPE 0.2f

#define GEMM_TILES 628        // (M_PAD/128) * (DIM_H/128) = 157*4
#define GEMM_GRID  632        // ceil to multiple of 8 for XCD swizzle

// sliced gather: 8 column slices (64 cols), slice = bid&7 -> XCD (round-robin).
// grid = 8 slices * 625 node-groups; block = 4 waves; wave = 8 slots * 8 subs;
// slot owns ONE node (degree-binned via perm), sub owns 8 cols (uint4).
#define SLC_GRID 5000

typedef __attribute__((ext_vector_type(8))) short short8;
typedef __attribute__((ext_vector_type(4))) float f32x4;

#define GPTR(p) (const __attribute__((address_space(1))) void*)(p)
#define LPTR(p) (__attribute__((address_space(3))) void*)(p)

__device__ __forceinline__ float bf2f(unsigned int lo16) {
  return __uint_as_float(lo16 << 16);
}
__device__ __forceinline__ unsigned short f2bf(float f) {
  unsigned int u = __float_as_uint(f);
  u += 0x7FFFu + ((u >> 16) & 1u);   // round-to-nearest-even
  return (unsigned short)(u >> 16);
}
__device__ __forceinline__ void unpack8(uint4 v, float* f) {
  f[0] = bf2f(v.x & 0xffffu); f[1] = bf2f(v.x >> 16);
  f[2] = bf2f(v.y & 0xffffu); f[3] = bf2f(v.y >> 16);
  f[4] = bf2f(v.z & 0xffffu); f[5] = bf2f(v.z >> 16);
  f[6] = bf2f(v.w & 0xffffu); f[7] = bf2f(v.w >> 16);
}
__device__ __forceinline__ uint4 pack8(const float* o) {
  uint4 pv;
  pv.x = (unsigned)f2bf(o[0]) | ((unsigned)f2bf(o[1]) << 16);
  pv.y = (unsigned)f2bf(o[2]) | ((unsigned)f2bf(o[3]) << 16);
  pv.z = (unsigned)f2bf(o[4]) | ((unsigned)f2bf(o[5]) << 16);
  pv.w = (unsigned)f2bf(o[6]) | ((unsigned)f2bf(o[7]) << 16);
  return pv;
}

__device__ __forceinline__ float waveReduceSum(float v) {
#pragma unroll
  for (int off = 32; off > 0; off >>= 1) v += __shfl_xor(v, off, 64);
  return v;
}
__device__ __forceinline__ float waveReduceMax(float v) {
#pragma unroll
  for (int off = 32; off > 0; off >>= 1) v = fmaxf(v, __shfl_xor(v, off, 64));
  return v;
}

// ============ MFMA GEMM: double-buffered LDS (1 barrier/K-step) + coalesced C ============
// Cbf[M_PAD,512](bf16) = A[M_PAD,K](bf16) @ Bt[512,K]^T (+bias). XCD tile swizzle.
__global__ __launch_bounds__(256) void gemm_mfma_bf16(
    const unsigned short* __restrict__ A,
    const unsigned short* __restrict__ Bt,
    const float* __restrict__ bias,
    unsigned short* __restrict__ Cbf,
    int K) {
  int bid = blockIdx.x;
  int tile = (bid & 7) * (GEMM_GRID / 8) + (bid >> 3);
  if (tile >= GEMM_TILES) return;
  int brow = tile >> 2;   // 0..156
  int bcol = tile & 3;    // 0..3

  // lds[0],lds[1] = A dbuf; lds[2],lds[3] = B dbuf; epilogue reuses lds[0..1] as Cs[128][128]
  __shared__ __align__(16) unsigned short lds[4][128 * 32];
  int tid = threadIdx.x;
  int wave = tid >> 6, lane = tid & 63;
  int wm = wave >> 1, wn = wave & 1;

  int rl = lane >> 2;
  int kc = (lane & 3) ^ ((lane >> 3) & 3);
  int r0 = 32 * wave;
  const unsigned short* gA0 = A + (size_t)(brow * 128 + r0 + rl) * K + kc * 8;
  const unsigned short* gA1 = gA0 + (size_t)16 * K;
  const unsigned short* gB0 = Bt + (size_t)(bcol * 128 + r0 + rl) * K + kc * 8;
  const unsigned short* gB1 = gB0 + (size_t)16 * K;

  int mrow = lane & 15;
  int q = lane >> 4;
  int swz = (q ^ ((mrow >> 1) & 3)) * 8;

  f32x4 acc[4][4];
#pragma unroll
  for (int i = 0; i < 4; ++i)
#pragma unroll
    for (int j = 0; j < 4; ++j) acc[i][j] = (f32x4)(0.f);

  int nk = K >> 5;
  {  // prologue: stage k-step 0 into buffer 0
    unsigned short* lA = lds[0] + r0 * 32;
    unsigned short* lB = lds[2] + r0 * 32;
    __builtin_amdgcn_global_load_lds(GPTR(gA0), LPTR(lA), 16, 0, 0);
    __builtin_amdgcn_global_load_lds(GPTR(gA1), LPTR(lA + 512), 16, 0, 0);
    __builtin_amdgcn_global_load_lds(GPTR(gB0), LPTR(lB), 16, 0, 0);
    __builtin_amdgcn_global_load_lds(GPTR(gB1), LPTR(lB + 512), 16, 0, 0);
  }
  __syncthreads();   // compiler drains vmcnt before barrier -> buf0 ready

  for (int t = 0; t < nk; ++t) {
    int cur = t & 1;
    if (t + 1 < nk) {   // stage next k-step into the other buffer (overlaps MFMA)
      int k0 = (t + 1) << 5;
      unsigned short* lA = lds[cur ^ 1] + r0 * 32;
      unsigned short* lB = lds[2 + (cur ^ 1)] + r0 * 32;
      __builtin_amdgcn_global_load_lds(GPTR(gA0 + k0), LPTR(lA), 16, 0, 0);
      __builtin_amdgcn_global_load_lds(GPTR(gA1 + k0), LPTR(lA + 512), 16, 0, 0);
      __builtin_amdgcn_global_load_lds(GPTR(gB0 + k0), LPTR(lB), 16, 0, 0);
      __builtin_amdgcn_global_load_lds(GPTR(gB1 + k0), LPTR(lB + 512), 16, 0, 0);
    }
    const short8* ra = (const short8*)(lds[cur] + (64 * wm + mrow) * 32 + swz);
    const short8* rb = (const short8*)(lds[2 + cur] + (64 * wn + mrow) * 32 + swz);
    short8 a[4], b[4];
#pragma unroll
    for (int u = 0; u < 4; ++u) a[u] = ra[u * 64];
#pragma unroll
    for (int u = 0; u < 4; ++u) b[u] = rb[u * 64];
#pragma unroll
    for (int mt = 0; mt < 4; ++mt)
#pragma unroll
      for (int nt = 0; nt < 4; ++nt)
        acc[mt][nt] = __builtin_amdgcn_mfma_f32_16x16x32_bf16(a[mt], b[nt], acc[mt][nt], 0, 0, 0);
    __syncthreads();   // one barrier per K-step: next buf staged AND all reads of cur done
  }

  // epilogue: stage C tile in LDS (reuse lds[0..1] = 32KB), then coalesced uint4 writes
  unsigned short* Cs = lds[0];
  {
    float bv[4];
#pragma unroll
    for (int nt = 0; nt < 4; ++nt)
      bv[nt] = bias ? bias[bcol * 128 + 64 * wn + 16 * nt + mrow] : 0.f;
#pragma unroll
    for (int mt = 0; mt < 4; ++mt)
#pragma unroll
      for (int nt = 0; nt < 4; ++nt)
#pragma unroll
        for (int i = 0; i < 4; ++i) {
          int row = 64 * wm + 16 * mt + 4 * q + i;
          int col = 64 * wn + 16 * nt + mrow;
          Cs[row * 128 + col] = f2bf(acc[mt][nt][i] + bv[nt]);
        }
  }
  __syncthreads();
  int rr = tid >> 4, cb = (tid & 15) * 8;
#pragma unroll
  for (int it = 0; it < 8; ++it, rr += 16) {
    uint4 val = *(const uint4*)(Cs + rr * 128 + cb);
    *(uint4*)(Cbf + (size_t)(brow * 128 + rr) * DIM_H + bcol * 128 + cb) = val;
  }
}

// ================= conversions =================
__global__ void convert_feat(const float* __restrict__ feat, unsigned short* __restrict__ Abf) {
  int t = blockIdx.x * blockDim.x + threadIdx.x;
  const int CHUNKS = M_PAD * DIM_IN / 8;
  if (t >= CHUNKS) return;
  int row = t / (DIM_IN / 8);
  uint4 o;
  if (row < N_NODES) {
    const float4* p = (const float4*)(feat + (size_t)t * 8);
    float4 x = p[0], y = p[1];
    o.x = (unsigned)f2bf(x.x) | ((unsigned)f2bf(x.y) << 16);
    o.y = (unsigned)f2bf(x.z) | ((unsigned)f2bf(x.w) << 16);
    o.z = (unsigned)f2bf(y.x) | ((unsigned)f2bf(y.y) << 16);
    o.w = (unsigned)f2bf(y.z) | ((unsigned)f2bf(y.w) << 16);
  } else {
    o = make_uint4(0, 0, 0, 0);
  }
  ((uint4*)Abf)[t] = o;
}

// LDS-tiled transpose: in [R,C] f32 -> out [C,R] bf16. R,C multiples of 32.
__global__ __launch_bounds__(256) void transpose_bf16(const float* __restrict__ in,
                                                      unsigned short* __restrict__ out,
                                                      int R, int C) {
  __shared__ float tile[32][33];
  int tx = threadIdx.x, ty = threadIdx.y;
  size_t base = (size_t)blockIdx.z * R * C;
  int r0 = blockIdx.x * 32, c0 = blockIdx.y * 32;
#pragma unroll
  for (int i = 0; i < 4; ++i) {
    int r = r0 + ty + i * 8;
    tile[ty + i * 8][tx] = in[base + (size_t)r * C + c0 + tx];
  }
  __syncthreads();
#pragma unroll
  for (int i = 0; i < 4; ++i) {
    int c = c0 + ty + i * 8;
    out[base + (size_t)c * R + r0 + tx] = f2bf(tile[tx][ty + i * 8]);
  }
}

// ================= CSR build (dst -> src adjacency) =================
__global__ void count_edges(const int* __restrict__ dst, int* __restrict__ counts) {
  int k = blockIdx.x * blockDim.x + threadIdx.x;
  if (k < N_EDGES) atomicAdd(&counts[dst[k]], 1);
}

__global__ __launch_bounds__(1024) void scan_kernel(const int* __restrict__ counts,
                                                    int* __restrict__ indptr) {
  __shared__ int part[1024];
  int tid = threadIdx.x;
  const int CH = (N_NODES + 1023) / 1024;
  int base = tid * CH;
  int s = 0;
  for (int i = 0; i < CH; ++i) {
    int idx = base + i;
    if (idx < N_NODES) s += counts[idx];
  }
  part[tid] = s;
  __syncthreads();
  for (int off = 1; off < 1024; off <<= 1) {
    int v = (tid >= off) ? part[tid - off] : 0;
    __syncthreads();
    part[tid] += v;
    __syncthreads();
  }
  int run = (tid == 0) ? 0 : part[tid - 1];
  for (int i = 0; i < CH; ++i) {
    int idx = base + i;
    if (idx < N_NODES) {
      indptr[idx] = run;
      run += counts[idx];
      if (idx == N_NODES - 1) indptr[N_NODES] = run;
    }
  }
}

__global__ void fill_adj(const int* __restrict__ src, const int* __restrict__ dst,
                         const int* __restrict__ indptr, int* __restrict__ cursor,
                         int* __restrict__ adjsrc) {
  int k = blockIdx.x * blockDim.x + threadIdx.x;
  if (k < N_EDGES) {
    int d = dst[k];
    int pos = atomicAdd(&cursor[d], 1);
    adjsrc[indptr[d] + pos] = src[k];
  }
}

// ============ degree binning in ONE block: LDS hist + LDS scan + LDS cursors ============
// (R6's global-atomic version serialized on 64 hot lines -> 54 us/kernel. LDS atomics
//  over 64 bins are ~cycles; total ~5 us.)
__global__ __launch_bounds__(1024) void build_perm(const int* __restrict__ counts,
                                                   int* __restrict__ perm) {
  __shared__ int hist[64];
  __shared__ int basec[64];
  int tid = threadIdx.x;
  if (tid < 64) hist[tid] = 0;
  __syncthreads();
  for (int v = tid; v < N_NODES; v += 1024)
    atomicAdd(&hist[min(counts[v], 63)], 1);
  __syncthreads();
  if (tid == 0) {
    int run = 0;
#pragma unroll
    for (int i = 0; i < 64; ++i) { basec[i] = run; run += hist[i]; }
  }
  __syncthreads();
  for (int v = tid; v < N_NODES; v += 1024) {
    int b = min(counts[v], 63);
    int pos = atomicAdd(&basec[b], 1);
    perm[pos] = v;
  }
}

// ================= el/er from bf16 z =================
__global__ __launch_bounds__(256) void eler_bf(const unsigned short* __restrict__ zbf,
                                               const float* __restrict__ al,
                                               const float* __restrict__ ar,
                                               float* __restrict__ el, float* __restrict__ er) {
  int wid = (blockIdx.x * blockDim.x + threadIdx.x) >> 6;
  int lane = threadIdx.x & 63;
  if (wid >= N_NODES) return;
  uint4 zv = ((const uint4*)(zbf + (size_t)wid * DIM_H))[lane];
  float z[8];
  unpack8(zv, z);
  const float4* al4 = (const float4*)(al + lane * 8);
  const float4* ar4 = (const float4*)(ar + lane * 8);
  float4 a0 = al4[0], a1 = al4[1], r0 = ar4[0], r1 = ar4[1];
  float sl = z[0] * a0.x + z[1] * a0.y + z[2] * a0.z + z[3] * a0.w +
             z[4] * a1.x + z[5] * a1.y + z[6] * a1.z + z[7] * a1.w;
  float sr = z[0] * r0.x + z[1] * r0.y + z[2] * r0.z + z[3] * r0.w +
             z[4] * r1.x + z[5] * r1.y + z[6] * r1.z + z[7] * r1.w;
  sl = waveReduceSum(sl);
  sr = waveReduceSum(sr);
  if (lane == 0) { el[wid] = sl; er[wid] = sr; }
}

// ================= edge softmax -> packed (idx, alpha) records =================
__global__ __launch_bounds__(256) void edge_softmax_alpha(
    const float* __restrict__ el, const float* __restrict__ er,
    const int* __restrict__ indptr, const int* __restrict__ adjsrc,
    float* __restrict__ alpha, int2* __restrict__ apairs) {
  int v = (blockIdx.x * blockDim.x + threadIdx.x) >> 6;
  int lane = threadIdx.x & 63;
  if (v >= N_NODES) return;
  int begin = indptr[v], end = indptr[v + 1];
  float er_v = er[v];

  float m = -INFINITY;
  for (int j = begin + lane; j < end; j += 64) {
    float e = el[adjsrc[j]] + er_v;
    e = (e >= 0.f) ? e : NEG_SLOPE * e;
    alpha[j] = e;
    m = fmaxf(m, e);
  }
  m = waveReduceMax(m);

  float ss = 0.f;
  for (int j = begin + lane; j < end; j += 64) {
    float ex = __expf(alpha[j] - m);
    alpha[j] = ex;
    ss += ex;
  }
  float denom = waveReduceSum(ss);
  float inv = (end > begin) ? 1.f / denom : 0.f;

  for (int j = begin + lane; j < end; j += 64)
    apairs[j] = make_int2(adjsrc[j], __float_as_int(alpha[j] * inv));
}

// ========== XCD-sliced gather, slot-per-node, degree-binned, 8-deep ILP ==========
// slice = bid&7 -> XCD (2.56 MB table slice resident in that XCD's 4 MiB L2).
// lane = (slot, sub): slot owns node perm[vidx] (degree-binned -> max degree of the
// wave's 8 slots ~= mean), sub owns 8 cols (uint4). 8 edges per iteration, all
// addresses uniform_base + 32-bit voffset; masked tail via weight 0.
__global__ __launch_bounds__(256) void gather_slc(
    const unsigned short* __restrict__ zin, const int2* __restrict__ apairs,
    const int* __restrict__ indptr, const int* __restrict__ adjsrc,
    const int* __restrict__ perm, const float* __restrict__ bias, int self_term,
    unsigned short* __restrict__ out_bf, float* __restrict__ out_f32) {
  int slice = blockIdx.x & 7;
  int grp = blockIdx.x >> 3;                    // 0..624
  int wave = threadIdx.x >> 6, lane = threadIdx.x & 63;
  int slot = lane >> 3, sub = lane & 7;
  int vidx = grp * 32 + wave * 8 + slot;
  int v = perm[vidx];                           // degree-binned node
  unsigned cbyte = (unsigned)(slice * 128 + sub * 16);
  const char* zb = (const char*)zin;

  int b = indptr[v];
  unsigned ue = (unsigned)indptr[v + 1];
  int md = (int)ue - b;                         // max degree over the 8 slots
  md = max(md, __shfl_xor(md, 8, 64));
  md = max(md, __shfl_xor(md, 16, 64));
  md = max(md, __shfl_xor(md, 32, 64));

  float acc[8];
  if (self_term) {
    uint4 sz = *(const uint4*)(zb + (((unsigned)v) << 10) + cbyte);
    unpack8(sz, acc);
  } else {
#pragma unroll
    for (int i = 0; i < 8; ++i) acc[i] = 0.f;
  }

  unsigned jb = (unsigned)b;
  const unsigned EMAX = (unsigned)(N_EDGES - 1);
  if (apairs) {
    const char* pb = (const char*)apairs;
#pragma nounroll
    for (int t = 0; t < md; t += 8) {
      unsigned j0 = jb + (unsigned)t;
      int idx[8];
      float wv[8];
#pragma unroll
      for (int u = 0; u < 8; ++u) {
        unsigned a = min(j0 + (unsigned)u, EMAX) << 3;
        int2 p = *(const int2*)(pb + a);
        idx[u] = p.x;
        wv[u] = (j0 + (unsigned)u < ue) ? __int_as_float(p.y) : 0.f;
      }
      uint4 z[8];
#pragma unroll
      for (int u = 0; u < 8; ++u)
        z[u] = *(const uint4*)(zb + (((unsigned)idx[u]) << 10) + cbyte);
#pragma unroll
      for (int u = 0; u < 8; ++u) {
        float f[8];
        unpack8(z[u], f);
#pragma unroll
        for (int i = 0; i < 8; ++i) acc[i] = fmaf(wv[u], f[i], acc[i]);
      }
    }
  } else {
    const char* ab = (const char*)adjsrc;
#pragma nounroll
    for (int t = 0; t < md; t += 8) {
      unsigned j0 = jb + (unsigned)t;
      int idx[8];
      float wv[8];
#pragma unroll
      for (int u = 0; u < 8; ++u) {
        unsigned a = min(j0 + (unsigned)u, EMAX) << 2;
        idx[u] = *(const int*)(ab + a);
        wv[u] = (j0 + (unsigned)u < ue) ? 1.f : 0.f;
      }
      uint4 z[8];
#pragma unroll
      for (int u = 0; u < 8; ++u)
        z[u] = *(const uint4*)(zb + (((unsigned)idx[u]) << 10) + cbyte);
#pragma unroll
      for (int u = 0; u < 8; ++u) {
        float f[8];
        unpack8(z[u], f);
#pragma unroll
        for (int i = 0; i < 8; ++i) acc[i] = fmaf(wv[u], f[i], acc[i]);
      }
    }
  }

  if (bias) {
    const float4* b4 = (const float4*)(bias + slice * 64 + sub * 8);
    float4 b0 = b4[0], b1 = b4[1];
    acc[0] += b0.x; acc[1] += b0.y; acc[2] += b0.z; acc[3] += b0.w;
    acc[4] += b1.x; acc[5] += b1.y; acc[6] += b1.z; acc[7] += b1.w;
  }
  if (out_bf) {
    uint4 pv = pack8(acc);
    *(uint4*)((char*)out_bf + (((unsigned)v) << 10) + cbyte) = pv;
  } else {
    char* p = (char*)out_f32 + (((unsigned)v) << 11) + cbyte * 2;
    *(f32x4*)p = (f32x4){acc[0], acc[1], acc[2], acc[3]};
    *(f32x4*)(p + 16) = (f32x4){acc[4], acc[5], acc[6], acc[7]};
  }
}

// ================= launch =================
extern "C" void kernel_launch(void* const* d_in, const int* in_sizes, int n_in,
                              void* d_out, int out_size, void* d_ws, size_t ws_size,
                              hipStream_t stream) {
  const float* feat = (const float*)d_in[0];
  const float* fc_W = (const float*)d_in[1];
  const float* fc_b = (const float*)d_in[2];
  const float* gat_W = (const float*)d_in[3];
  const float* gat_al = (const float*)d_in[4];
  const float* gat_ar = (const float*)d_in[5];
  const float* gat_b = (const float*)d_in[6];
  // d_in[7] = beta unused (reference returns Z_prev)
  const int* src = (const int*)d_in[8];
  const int* dst = (const int*)d_in[9];
  float* out = (float*)d_out;

  char* w = (char*)d_ws;
  auto alloc = [&](size_t bytes) {
    char* p = w;
    w += (bytes + 255) & ~(size_t)255;
    return p;
  };
  unsigned short* hbf   = (unsigned short*)alloc((size_t)M_PAD * DIM_H * 2);
  unsigned short* fcWt  = (unsigned short*)alloc((size_t)DIM_H * DIM_IN * 2);
  unsigned short* gatWt = (unsigned short*)alloc((size_t)NUM_GNNS * DIM_H * DIM_H * 2);
  float* el    = (float*)alloc((size_t)N_NODES * 4);
  float* er    = (float*)alloc((size_t)N_NODES * 4);
  int* counts  = (int*)alloc((size_t)2 * N_NODES * 4);   // counts+cursor contiguous
  int* cursor  = counts + N_NODES;
  int* indptr  = (int*)alloc((size_t)(N_NODES + 1) * 4);
  int* adjsrc  = (int*)alloc((size_t)N_EDGES * 4);
  int* perm    = (int*)alloc((size_t)N_NODES * 4);
  char* uni = alloc((size_t)M_PAD * DIM_IN * 2);   // Abf (30.9MB) -> alpha+apairs -> Z1 (20.6MB)
  unsigned short* Abf = (unsigned short*)uni;      // live: convert + first GEMM only
  float* alpha = (float*)uni;                      // live: softmax scratch per layer
  int2* apairs = (int2*)(uni + (((size_t)N_EDGES * 4 + 255) & ~(size_t)255)); // packed records
  unsigned short* Z1  = (unsigned short*)uni;      // live: propagation only
  unsigned short* zbf = (unsigned short*)d_out;

  // ---- CSR build + degree binning (single-block LDS binning: no global atomics) ----
  hipMemsetAsync(counts, 0, sizeof(int) * 2 * N_NODES, stream);
  count_edges<<<(N_EDGES + 255) / 256, 256, 0, stream>>>(dst, counts);
  scan_kernel<<<1, 1024, 0, stream>>>(counts, indptr);
  fill_adj<<<(N_EDGES + 255) / 256, 256, 0, stream>>>(src, dst, indptr, cursor, adjsrc);
  build_perm<<<1, 1024, 0, stream>>>(counts, perm);

  // ---- bf16 prep ----
  convert_feat<<<(M_PAD * DIM_IN / 8 + 255) / 256, 256, 0, stream>>>(feat, Abf);
  transpose_bf16<<<dim3(DIM_IN / 32, DIM_H / 32, 1), dim3(32, 8), 0, stream>>>(fc_W, fcWt, DIM_IN, DIM_H);
  transpose_bf16<<<dim3(DIM_H / 32, DIM_H / 32, NUM_GNNS), dim3(32, 8), 0, stream>>>(gat_W, gatWt, DIM_H, DIM_H);

  gemm_mfma_bf16<<<GEMM_GRID, 256, 0, stream>>>(Abf, fcWt, fc_b, hbf, DIM_IN);

  int nwaveblocks = (N_NODES * 64 + 255) / 256;
  for (int l = 0; l < NUM_GNNS; ++l) {
    gemm_mfma_bf16<<<GEMM_GRID, 256, 0, stream>>>(hbf, gatWt + (size_t)l * DIM_H * DIM_H,
                                                  nullptr, zbf, DIM_H);
    eler_bf<<<nwaveblocks, 256, 0, stream>>>(zbf, gat_al + (size_t)l * DIM_H,
                                             gat_ar + (size_t)l * DIM_H, el, er);
    edge_softmax_alpha<<<nwaveblocks, 256, 0, stream>>>(el, er, indptr, adjsrc, alpha, apairs);
    gather_slc<<<SLC_GRID, 256, 0, stream>>>(
        zbf, apairs, indptr, adjsrc, perm, gat_b + (size_t)l * DIM_H, 0, hbf, nullptr);
  }

  // ---- 3 propagation hops (self term, weight 1) ----
  gather_slc<<<SLC_GRID, 256, 0, stream>>>(hbf, nullptr, indptr, adjsrc, perm, nullptr, 1, Z1, nullptr);
  gather_slc<<<SLC_GRID, 256, 0, stream>>>(Z1, nullptr, indptr, adjsrc, perm, nullptr, 1, hbf, nullptr);
  gather_slc<<<SLC_GRID, 256, 0, stream>>>(hbf, nullptr, indptr, adjsrc, perm, nullptr, 1, nullptr, out);
}

// Round 8
// 581.730 us; speedup vs baseline: 1.2033x; 1.0243x over previous
//
#include <hip/hip_runtime.h>
#include <math.h>

#define N_NODES 20000
#define M_PAD   20096   // 157 * 128
#define N_EDGES 320000
#define DIM_IN 768
#define DIM_H 512
#define NUM_GNNS 4
#define NEG_SLOPE 0.2f

#define GEMM_TILES 628        // (M_PAD/128) * (DIM_H/128) = 157*4
#define GEMM_GRID  632        // ceil to multiple of 8 for XCD swizzle

// sliced gather: 8 column slices (64 cols), slice = bid&7 -> XCD (round-robin).
// grid = 8 slices * 625 node-groups; block = 4 waves; wave = 8 slots * 8 subs;
// slot owns ONE node (consecutive), sub owns 8 cols (uint4).
#define SLC_GRID 5000

typedef __attribute__((ext_vector_type(8))) short short8;
typedef __attribute__((ext_vector_type(4))) float f32x4;

#define GPTR(p) (const __attribute__((address_space(1))) void*)(p)
#define LPTR(p) (__attribute__((address_space(3))) void*)(p)

__device__ __forceinline__ float bf2f(unsigned int lo16) {
  return __uint_as_float(lo16 << 16);
}
__device__ __forceinline__ unsigned short f2bf(float f) {
  unsigned int u = __float_as_uint(f);
  u += 0x7FFFu + ((u >> 16) & 1u);   // round-to-nearest-even
  return (unsigned short)(u >> 16);
}
__device__ __forceinline__ void unpack8(uint4 v, float* f) {
  f[0] = bf2f(v.x & 0xffffu); f[1] = bf2f(v.x >> 16);
  f[2] = bf2f(v.y & 0xffffu); f[3] = bf2f(v.y >> 16);
  f[4] = bf2f(v.z & 0xffffu); f[5] = bf2f(v.z >> 16);
  f[6] = bf2f(v.w & 0xffffu); f[7] = bf2f(v.w >> 16);
}
__device__ __forceinline__ uint4 pack8(const float* o) {
  uint4 pv;
  pv.x = (unsigned)f2bf(o[0]) | ((unsigned)f2bf(o[1]) << 16);
  pv.y = (unsigned)f2bf(o[2]) | ((unsigned)f2bf(o[3]) << 16);
  pv.z = (unsigned)f2bf(o[4]) | ((unsigned)f2bf(o[5]) << 16);
  pv.w = (unsigned)f2bf(o[6]) | ((unsigned)f2bf(o[7]) << 16);
  return pv;
}

__device__ __forceinline__ float waveReduceSum(float v) {
#pragma unroll
  for (int off = 32; off > 0; off >>= 1) v += __shfl_xor(v, off, 64);
  return v;
}
__device__ __forceinline__ float waveReduceMax(float v) {
#pragma unroll
  for (int off = 32; off > 0; off >>= 1) v = fmaxf(v, __shfl_xor(v, off, 64));
  return v;
}

// ============ MFMA GEMM: double-buffered LDS (1 barrier/K-step) + coalesced C ============
// Cbf[M_PAD,512](bf16) = A[M_PAD,K](bf16) @ Bt[512,K]^T (+bias). XCD tile swizzle.
__global__ __launch_bounds__(256) void gemm_mfma_bf16(
    const unsigned short* __restrict__ A,
    const unsigned short* __restrict__ Bt,
    const float* __restrict__ bias,
    unsigned short* __restrict__ Cbf,
    int K) {
  int bid = blockIdx.x;
  int tile = (bid & 7) * (GEMM_GRID / 8) + (bid >> 3);
  if (tile >= GEMM_TILES) return;
  int brow = tile >> 2;   // 0..156
  int bcol = tile & 3;    // 0..3

  // lds[0],lds[1] = A dbuf; lds[2],lds[3] = B dbuf; epilogue reuses lds[0..1] as Cs[128][128]
  __shared__ __align__(16) unsigned short lds[4][128 * 32];
  int tid = threadIdx.x;
  int wave = tid >> 6, lane = tid & 63;
  int wm = wave >> 1, wn = wave & 1;

  int rl = lane >> 2;
  int kc = (lane & 3) ^ ((lane >> 3) & 3);
  int r0 = 32 * wave;
  const unsigned short* gA0 = A + (size_t)(brow * 128 + r0 + rl) * K + kc * 8;
  const unsigned short* gA1 = gA0 + (size_t)16 * K;
  const unsigned short* gB0 = Bt + (size_t)(bcol * 128 + r0 + rl) * K + kc * 8;
  const unsigned short* gB1 = gB0 + (size_t)16 * K;

  int mrow = lane & 15;
  int q = lane >> 4;
  int swz = (q ^ ((mrow >> 1) & 3)) * 8;

  f32x4 acc[4][4];
#pragma unroll
  for (int i = 0; i < 4; ++i)
#pragma unroll
    for (int j = 0; j < 4; ++j) acc[i][j] = (f32x4)(0.f);

  int nk = K >> 5;
  {  // prologue: stage k-step 0 into buffer 0
    unsigned short* lA = lds[0] + r0 * 32;
    unsigned short* lB = lds[2] + r0 * 32;
    __builtin_amdgcn_global_load_lds(GPTR(gA0), LPTR(lA), 16, 0, 0);
    __builtin_amdgcn_global_load_lds(GPTR(gA1), LPTR(lA + 512), 16, 0, 0);
    __builtin_amdgcn_global_load_lds(GPTR(gB0), LPTR(lB), 16, 0, 0);
    __builtin_amdgcn_global_load_lds(GPTR(gB1), LPTR(lB + 512), 16, 0, 0);
  }
  __syncthreads();   // compiler drains vmcnt before barrier -> buf0 ready

  for (int t = 0; t < nk; ++t) {
    int cur = t & 1;
    if (t + 1 < nk) {   // stage next k-step into the other buffer (overlaps MFMA)
      int k0 = (t + 1) << 5;
      unsigned short* lA = lds[cur ^ 1] + r0 * 32;
      unsigned short* lB = lds[2 + (cur ^ 1)] + r0 * 32;
      __builtin_amdgcn_global_load_lds(GPTR(gA0 + k0), LPTR(lA), 16, 0, 0);
      __builtin_amdgcn_global_load_lds(GPTR(gA1 + k0), LPTR(lA + 512), 16, 0, 0);
      __builtin_amdgcn_global_load_lds(GPTR(gB0 + k0), LPTR(lB), 16, 0, 0);
      __builtin_amdgcn_global_load_lds(GPTR(gB1 + k0), LPTR(lB + 512), 16, 0, 0);
    }
    const short8* ra = (const short8*)(lds[cur] + (64 * wm + mrow) * 32 + swz);
    const short8* rb = (const short8*)(lds[2 + cur] + (64 * wn + mrow) * 32 + swz);
    short8 a[4], b[4];
#pragma unroll
    for (int u = 0; u < 4; ++u) a[u] = ra[u * 64];
#pragma unroll
    for (int u = 0; u < 4; ++u) b[u] = rb[u * 64];
#pragma unroll
    for (int mt = 0; mt < 4; ++mt)
#pragma unroll
      for (int nt = 0; nt < 4; ++nt)
        acc[mt][nt] = __builtin_amdgcn_mfma_f32_16x16x32_bf16(a[mt], b[nt], acc[mt][nt], 0, 0, 0);
    __syncthreads();   // one barrier per K-step: next buf staged AND all reads of cur done
  }

  // epilogue: stage C tile in LDS (reuse lds[0..1] = 32KB), then coalesced uint4 writes
  unsigned short* Cs = lds[0];
  {
    float bv[4];
#pragma unroll
    for (int nt = 0; nt < 4; ++nt)
      bv[nt] = bias ? bias[bcol * 128 + 64 * wn + 16 * nt + mrow] : 0.f;
#pragma unroll
    for (int mt = 0; mt < 4; ++mt)
#pragma unroll
      for (int nt = 0; nt < 4; ++nt)
#pragma unroll
        for (int i = 0; i < 4; ++i) {
          int row = 64 * wm + 16 * mt + 4 * q + i;
          int col = 64 * wn + 16 * nt + mrow;
          Cs[row * 128 + col] = f2bf(acc[mt][nt][i] + bv[nt]);
        }
  }
  __syncthreads();
  int rr = tid >> 4, cb = (tid & 15) * 8;
#pragma unroll
  for (int it = 0; it < 8; ++it, rr += 16) {
    uint4 val = *(const uint4*)(Cs + rr * 128 + cb);
    *(uint4*)(Cbf + (size_t)(brow * 128 + rr) * DIM_H + bcol * 128 + cb) = val;
  }
}

// ================= conversions =================
__global__ void convert_feat(const float* __restrict__ feat, unsigned short* __restrict__ Abf) {
  int t = blockIdx.x * blockDim.x + threadIdx.x;
  const int CHUNKS = M_PAD * DIM_IN / 8;
  if (t >= CHUNKS) return;
  int row = t / (DIM_IN / 8);
  uint4 o;
  if (row < N_NODES) {
    const float4* p = (const float4*)(feat + (size_t)t * 8);
    float4 x = p[0], y = p[1];
    o.x = (unsigned)f2bf(x.x) | ((unsigned)f2bf(x.y) << 16);
    o.y = (unsigned)f2bf(x.z) | ((unsigned)f2bf(x.w) << 16);
    o.z = (unsigned)f2bf(y.x) | ((unsigned)f2bf(y.y) << 16);
    o.w = (unsigned)f2bf(y.z) | ((unsigned)f2bf(y.w) << 16);
  } else {
    o = make_uint4(0, 0, 0, 0);
  }
  ((uint4*)Abf)[t] = o;
}

// LDS-tiled transpose: in [R,C] f32 -> out [C,R] bf16. R,C multiples of 32.
__global__ __launch_bounds__(256) void transpose_bf16(const float* __restrict__ in,
                                                      unsigned short* __restrict__ out,
                                                      int R, int C) {
  __shared__ float tile[32][33];
  int tx = threadIdx.x, ty = threadIdx.y;
  size_t base = (size_t)blockIdx.z * R * C;
  int r0 = blockIdx.x * 32, c0 = blockIdx.y * 32;
#pragma unroll
  for (int i = 0; i < 4; ++i) {
    int r = r0 + ty + i * 8;
    tile[ty + i * 8][tx] = in[base + (size_t)r * C + c0 + tx];
  }
  __syncthreads();
#pragma unroll
  for (int i = 0; i < 4; ++i) {
    int c = c0 + ty + i * 8;
    out[base + (size_t)c * R + r0 + tx] = f2bf(tile[tx][ty + i * 8]);
  }
}

// ================= CSR build (dst -> src adjacency) =================
__global__ void count_edges(const int* __restrict__ dst, int* __restrict__ counts) {
  int k = blockIdx.x * blockDim.x + threadIdx.x;
  if (k < N_EDGES) atomicAdd(&counts[dst[k]], 1);
}

__global__ __launch_bounds__(1024) void scan_kernel(const int* __restrict__ counts,
                                                    int* __restrict__ indptr) {
  __shared__ int part[1024];
  int tid = threadIdx.x;
  const int CH = (N_NODES + 1023) / 1024;
  int base = tid * CH;
  int s = 0;
  for (int i = 0; i < CH; ++i) {
    int idx = base + i;
    if (idx < N_NODES) s += counts[idx];
  }
  part[tid] = s;
  __syncthreads();
  for (int off = 1; off < 1024; off <<= 1) {
    int v = (tid >= off) ? part[tid - off] : 0;
    __syncthreads();
    part[tid] += v;
    __syncthreads();
  }
  int run = (tid == 0) ? 0 : part[tid - 1];
  for (int i = 0; i < CH; ++i) {
    int idx = base + i;
    if (idx < N_NODES) {
      indptr[idx] = run;
      run += counts[idx];
      if (idx == N_NODES - 1) indptr[N_NODES] = run;
    }
  }
}

__global__ void fill_adj(const int* __restrict__ src, const int* __restrict__ dst,
                         const int* __restrict__ indptr, int* __restrict__ cursor,
                         int* __restrict__ adjsrc) {
  int k = blockIdx.x * blockDim.x + threadIdx.x;
  if (k < N_EDGES) {
    int d = dst[k];
    int pos = atomicAdd(&cursor[d], 1);
    adjsrc[indptr[d] + pos] = src[k];
  }
}

// ============ weight-1 records for propagation hops ============
__global__ void pack_ones(const int* __restrict__ adjsrc, int2* __restrict__ apairs) {
  int k = blockIdx.x * blockDim.x + threadIdx.x;
  if (k < N_EDGES) apairs[k] = make_int2(adjsrc[k], __float_as_int(1.0f));
}

// ================= el/er from bf16 z =================
__global__ __launch_bounds__(256) void eler_bf(const unsigned short* __restrict__ zbf,
                                               const float* __restrict__ al,
                                               const float* __restrict__ ar,
                                               float* __restrict__ el, float* __restrict__ er) {
  int wid = (blockIdx.x * blockDim.x + threadIdx.x) >> 6;
  int lane = threadIdx.x & 63;
  if (wid >= N_NODES) return;
  uint4 zv = ((const uint4*)(zbf + (size_t)wid * DIM_H))[lane];
  float z[8];
  unpack8(zv, z);
  const float4* al4 = (const float4*)(al + lane * 8);
  const float4* ar4 = (const float4*)(ar + lane * 8);
  float4 a0 = al4[0], a1 = al4[1], r0 = ar4[0], r1 = ar4[1];
  float sl = z[0] * a0.x + z[1] * a0.y + z[2] * a0.z + z[3] * a0.w +
             z[4] * a1.x + z[5] * a1.y + z[6] * a1.z + z[7] * a1.w;
  float sr = z[0] * r0.x + z[1] * r0.y + z[2] * r0.z + z[3] * r0.w +
             z[4] * r1.x + z[5] * r1.y + z[6] * r1.z + z[7] * r1.w;
  sl = waveReduceSum(sl);
  sr = waveReduceSum(sr);
  if (lane == 0) { el[wid] = sl; er[wid] = sr; }
}

// ================= edge softmax -> packed (idx, alpha) records =================
__global__ __launch_bounds__(256) void edge_softmax_alpha(
    const float* __restrict__ el, const float* __restrict__ er,
    const int* __restrict__ indptr, const int* __restrict__ adjsrc,
    float* __restrict__ alpha, int2* __restrict__ apairs) {
  int v = (blockIdx.x * blockDim.x + threadIdx.x) >> 6;
  int lane = threadIdx.x & 63;
  if (v >= N_NODES) return;
  int begin = indptr[v], end = indptr[v + 1];
  float er_v = er[v];

  float m = -INFINITY;
  for (int j = begin + lane; j < end; j += 64) {
    float e = el[adjsrc[j]] + er_v;
    e = (e >= 0.f) ? e : NEG_SLOPE * e;
    alpha[j] = e;
    m = fmaxf(m, e);
  }
  m = waveReduceMax(m);

  float ss = 0.f;
  for (int j = begin + lane; j < end; j += 64) {
    float ex = __expf(alpha[j] - m);
    alpha[j] = ex;
    ss += ex;
  }
  float denom = waveReduceSum(ss);
  float inv = (end > begin) ? 1.f / denom : 0.f;

  for (int j = begin + lane; j < end; j += 64)
    apairs[j] = make_int2(adjsrc[j], __float_as_int(alpha[j] * inv));
}

// ========== XCD-sliced gather, slot-per-node, 2-stage record prefetch ==========
// slice = bid&7 -> XCD (2.56 MB table slice resident in that XCD's 4 MiB L2).
// lane = (slot, sub): slot owns one of 8 CONSECUTIVE nodes (contiguous edge
// streams / self-reads / stores -> minimal HBM), sub owns 8 cols (uint4).
// Per 8-edge batch: next batch's (idx,alpha) records are loaded BEFORE the
// current batch's gathers+fmas, so the record-load latency hides under compute
// (breaks the idx->gather serial chain that bounded R5-R7 at ~41 us).
// Reads past a node's degree stay in padded record memory; gather index is
// umin-clamped; weight forced 0 by (u < rem).
__global__ __launch_bounds__(256) void gather_slc(
    const unsigned short* __restrict__ zin, const int2* __restrict__ apairs,
    const int* __restrict__ indptr, const float* __restrict__ bias, int self_term,
    unsigned short* __restrict__ out_bf, float* __restrict__ out_f32) {
  int slice = blockIdx.x & 7;
  int grp = blockIdx.x >> 3;                    // 0..624
  int wave = threadIdx.x >> 6, lane = threadIdx.x & 63;
  int slot = lane >> 3, sub = lane & 7;
  int v = grp * 32 + wave * 8 + slot;           // consecutive nodes per wave
  unsigned cbyte = (unsigned)(slice * 128 + sub * 16);
  const char* zb = (const char*)zin;
  const char* pb = (const char*)apairs;

  int b = indptr[v];
  int deg = indptr[v + 1] - b;
  int md = deg;                                 // max degree over the 8 slots
  md = max(md, __shfl_xor(md, 8, 64));
  md = max(md, __shfl_xor(md, 16, 64));
  md = max(md, __shfl_xor(md, 32, 64));

  float acc[8];
  if (self_term) {
    uint4 sz = *(const uint4*)(zb + (((unsigned)v) << 10) + cbyte);
    unpack8(sz, acc);
  } else {
#pragma unroll
    for (int i = 0; i < 8; ++i) acc[i] = 0.f;
  }

  const unsigned NMAX = (unsigned)(N_NODES - 1);
  unsigned ab = ((unsigned)b) << 3;
  int2 ra[8];
#pragma unroll
  for (int u = 0; u < 8; ++u) ra[u] = *(const int2*)(pb + ab + u * 8);
#pragma nounroll
  for (int t = 0; t < md; t += 8) {
    int2 rn[8];
    if (t + 8 < md) {                           // wave-uniform branch
#pragma unroll
      for (int u = 0; u < 8; ++u) rn[u] = *(const int2*)(pb + ab + 64 + u * 8);
    } else {
#pragma unroll
      for (int u = 0; u < 8; ++u) rn[u] = ra[u];
    }
    int rem = deg - t;
#pragma unroll
    for (int u = 0; u < 8; ++u) {
      unsigned uidx = min((unsigned)ra[u].x, NMAX);
      float wv = (u < rem) ? __int_as_float(ra[u].y) : 0.f;
      uint4 z = *(const uint4*)(zb + (uidx << 10) + cbyte);
      float f[8];
      unpack8(z, f);
#pragma unroll
      for (int i = 0; i < 8; ++i) acc[i] = fmaf(wv, f[i], acc[i]);
    }
#pragma unroll
    for (int u = 0; u < 8; ++u) ra[u] = rn[u];
    ab += 64;
  }

  if (bias) {
    const float4* b4 = (const float4*)(bias + slice * 64 + sub * 8);
    float4 b0 = b4[0], b1 = b4[1];
    acc[0] += b0.x; acc[1] += b0.y; acc[2] += b0.z; acc[3] += b0.w;
    acc[4] += b1.x; acc[5] += b1.y; acc[6] += b1.z; acc[7] += b1.w;
  }
  if (out_bf) {
    uint4 pv = pack8(acc);
    *(uint4*)((char*)out_bf + (((unsigned)v) << 10) + cbyte) = pv;
  } else {
    char* p = (char*)out_f32 + (((unsigned)v) << 11) + cbyte * 2;
    *(f32x4*)p = (f32x4){acc[0], acc[1], acc[2], acc[3]};
    *(f32x4*)(p + 16) = (f32x4){acc[4], acc[5], acc[6], acc[7]};
  }
}

// ================= launch =================
extern "C" void kernel_launch(void* const* d_in, const int* in_sizes, int n_in,
                              void* d_out, int out_size, void* d_ws, size_t ws_size,
                              hipStream_t stream) {
  const float* feat = (const float*)d_in[0];
  const float* fc_W = (const float*)d_in[1];
  const float* fc_b = (const float*)d_in[2];
  const float* gat_W = (const float*)d_in[3];
  const float* gat_al = (const float*)d_in[4];
  const float* gat_ar = (const float*)d_in[5];
  const float* gat_b = (const float*)d_in[6];
  // d_in[7] = beta unused (reference returns Z_prev)
  const int* src = (const int*)d_in[8];
  const int* dst = (const int*)d_in[9];
  float* out = (float*)d_out;

  char* w = (char*)d_ws;
  auto alloc = [&](size_t bytes) {
    char* p = w;
    w += (bytes + 255) & ~(size_t)255;
    return p;
  };
  unsigned short* hbf   = (unsigned short*)alloc((size_t)M_PAD * DIM_H * 2);
  unsigned short* fcWt  = (unsigned short*)alloc((size_t)DIM_H * DIM_IN * 2);
  unsigned short* gatWt = (unsigned short*)alloc((size_t)NUM_GNNS * DIM_H * DIM_H * 2);
  float* el    = (float*)alloc((size_t)N_NODES * 4);
  float* er    = (float*)alloc((size_t)N_NODES * 4);
  int* counts  = (int*)alloc((size_t)2 * N_NODES * 4);   // counts+cursor contiguous
  int* cursor  = counts + N_NODES;
  int* indptr  = (int*)alloc((size_t)(N_NODES + 1) * 4);
  int* adjsrc  = (int*)alloc((size_t)(N_EDGES + 64) * 4); // +pad for overshoot reads
  char* uni = alloc((size_t)M_PAD * DIM_IN * 2);   // 30.9 MB union region
  unsigned short* Abf = (unsigned short*)uni;      // live: convert + first GEMM only
  float* alpha = (float*)uni;                      // live: softmax scratch per layer (1.28 MB)
  unsigned short* Z1  = (unsigned short*)uni;      // live: propagation ping buffer (20.6 MB)
  // packed records at uni+20.6MB: disjoint from Z1 AND from alpha -> usable in both phases
  int2* apairs = (int2*)(uni + (size_t)M_PAD * DIM_H * 2);  // 2.56 MB + pad, fits in 30.9
  unsigned short* zbf = (unsigned short*)d_out;

  // ---- CSR build ----
  hipMemsetAsync(counts, 0, sizeof(int) * 2 * N_NODES, stream);
  count_edges<<<(N_EDGES + 255) / 256, 256, 0, stream>>>(dst, counts);
  scan_kernel<<<1, 1024, 0, stream>>>(counts, indptr);
  fill_adj<<<(N_EDGES + 255) / 256, 256, 0, stream>>>(src, dst, indptr, cursor, adjsrc);

  // ---- bf16 prep ----
  convert_feat<<<(M_PAD * DIM_IN / 8 + 255) / 256, 256, 0, stream>>>(feat, Abf);
  transpose_bf16<<<dim3(DIM_IN / 32, DIM_H / 32, 1), dim3(32, 8), 0, stream>>>(fc_W, fcWt, DIM_IN, DIM_H);
  transpose_bf16<<<dim3(DIM_H / 32, DIM_H / 32, NUM_GNNS), dim3(32, 8), 0, stream>>>(gat_W, gatWt, DIM_H, DIM_H);

  gemm_mfma_bf16<<<GEMM_GRID, 256, 0, stream>>>(Abf, fcWt, fc_b, hbf, DIM_IN);

  int nwaveblocks = (N_NODES * 64 + 255) / 256;
  for (int l = 0; l < NUM_GNNS; ++l) {
    gemm_mfma_bf16<<<GEMM_GRID, 256, 0, stream>>>(hbf, gatWt + (size_t)l * DIM_H * DIM_H,
                                                  nullptr, zbf, DIM_H);
    eler_bf<<<nwaveblocks, 256, 0, stream>>>(zbf, gat_al + (size_t)l * DIM_H,
                                             gat_ar + (size_t)l * DIM_H, el, er);
    edge_softmax_alpha<<<nwaveblocks, 256, 0, stream>>>(el, er, indptr, adjsrc, alpha, apairs);
    gather_slc<<<SLC_GRID, 256, 0, stream>>>(
        zbf, apairs, indptr, gat_b + (size_t)l * DIM_H, 0, hbf, nullptr);
  }

  // ---- 3 propagation hops: weight-1 records, same pipelined gather ----
  pack_ones<<<(N_EDGES + 255) / 256, 256, 0, stream>>>(adjsrc, apairs);
  gather_slc<<<SLC_GRID, 256, 0, stream>>>(hbf, apairs, indptr, nullptr, 1, Z1, nullptr);
  gather_slc<<<SLC_GRID, 256, 0, stream>>>(Z1, apairs, indptr, nullptr, 1, hbf, nullptr);
  gather_slc<<<SLC_GRID, 256, 0, stream>>>(hbf, apairs, indptr, nullptr, 1, nullptr, out);
}